// Round 4
// baseline (355.540 us; speedup 1.0000x reference)
//
#include <hip/hip_runtime.h>

// Embedding lookup sparse (combiner='sum') for MI355X.
// keys:  int32 [N=106496, NNZ=10]
// mask:  bool in reference -> delivered as int32 [N, NNZ] by the harness
// table: fp32  [VOCAB=1e6, DIM=64]  (~244 MiB, ~L3-sized)
// out:   fp32  [N, DIM]  == reshape(BATCH, SLOTS*DIM), same memory layout

constexpr int NNZ   = 10;
constexpr int NROWS = 4096 * 26;   // 106496
constexpr int DIM   = 64;

__global__ __launch_bounds__(256) void emb_pool_kernel(
    const int* __restrict__ keys,
    const int* __restrict__ mask,     // int32: 0 or 1 per (row, j)
    const float* __restrict__ table,
    float* __restrict__ out)
{
    const int tid      = threadIdx.x;
    const int g        = tid & 15;        // float4 slice within the row (16 B/lane)
    const int rowLocal = tid >> 4;        // 0..15
    const int row      = blockIdx.x * 16 + rowLocal;
    if (row >= NROWS) return;

    const int* krow = keys + (size_t)row * NNZ;
    const int* mrow = mask + (size_t)row * NNZ;

    float4 acc = make_float4(0.f, 0.f, 0.f, 0.f);
#pragma unroll
    for (int j = 0; j < NNZ; ++j) {
        // Per-lane predication: masked positions issue NO table traffic.
        if (mrow[j] != 0) {
            const float4 v = *reinterpret_cast<const float4*>(
                table + (size_t)krow[j] * DIM + g * 4);
            acc.x += v.x; acc.y += v.y; acc.z += v.z; acc.w += v.w;
        }
    }
    *reinterpret_cast<float4*>(out + (size_t)row * DIM + g * 4) = acc;
}

extern "C" void kernel_launch(void* const* d_in, const int* in_sizes, int n_in,
                              void* d_out, int out_size, void* d_ws, size_t ws_size,
                              hipStream_t stream) {
    const int*   keys  = (const int*)d_in[0];
    const int*   mask  = (const int*)d_in[1];
    const float* table = (const float*)d_in[2];
    float*       out   = (float*)d_out;

    // 16 rows per 256-thread block; N = 106496 = 6656 * 16 (no tail).
    const int blocks = NROWS / 16;
    emb_pool_kernel<<<blocks, 256, 0, stream>>>(keys, mask, table, out);
}

// Round 6
// 342.488 us; speedup vs baseline: 1.0381x; 1.0381x over previous
//
#include <hip/hip_runtime.h>

// Embedding lookup sparse (combiner='sum') for MI355X.
// keys:  int32 [N=106496, NNZ=10]
// mask:  bool in reference -> delivered as int32 [N, NNZ] by the harness
// table: fp32  [VOCAB=1e6, DIM=64]  (~244 MiB, ~L3-sized)
// out:   fp32  [N, DIM]  == reshape(BATCH, SLOTS*DIM), same memory layout
//
// Branchless design: the predicated (`if mask`) version wraps every gather
// in exec-mask regions, serializing the 10 loads. Here all 10 gathers issue
// unconditionally back-to-back (full ILP, one vmcnt countdown), and the mask
// is applied as a float FMA (exact for 0/1 masks on finite table values).

constexpr int NNZ   = 10;
constexpr int NROWS = 4096 * 26;   // 106496
constexpr int DIM   = 64;

__global__ __launch_bounds__(256) void emb_pool_kernel(
    const int* __restrict__ keys,
    const int* __restrict__ mask,     // int32: 0 or 1 per (row, j)
    const float* __restrict__ table,
    float* __restrict__ out)
{
    const int tid      = threadIdx.x;
    const int g        = tid & 15;        // float4 slice within the row (16 B/lane)
    const int rowLocal = tid >> 4;        // 0..15
    const int row      = blockIdx.x * 16 + rowLocal;

    const int* krow = keys + (size_t)row * NNZ;
    const int* mrow = mask + (size_t)row * NNZ;

    // Key/mask rows are 40 B (8 B-aligned) -> int2 vector loads, 10 VMEM
    // ops instead of 20 scalar dwords.
    int k[NNZ], m[NNZ];
#pragma unroll
    for (int j = 0; j < NNZ; j += 2) {
        *reinterpret_cast<int2*>(k + j) = *reinterpret_cast<const int2*>(krow + j);
        *reinterpret_cast<int2*>(m + j) = *reinterpret_cast<const int2*>(mrow + j);
    }

    // All 10 gathers in flight at once.
    float4 v[NNZ];
#pragma unroll
    for (int j = 0; j < NNZ; ++j) {
        v[j] = *reinterpret_cast<const float4*>(
            table + (size_t)k[j] * DIM + g * 4);
    }

    float4 acc = make_float4(0.f, 0.f, 0.f, 0.f);
#pragma unroll
    for (int j = 0; j < NNZ; ++j) {
        const float mf = (float)m[j];   // 0.0f or 1.0f
        acc.x = fmaf(mf, v[j].x, acc.x);
        acc.y = fmaf(mf, v[j].y, acc.y);
        acc.z = fmaf(mf, v[j].z, acc.z);
        acc.w = fmaf(mf, v[j].w, acc.w);
    }
    *reinterpret_cast<float4*>(out + (size_t)row * DIM + g * 4) = acc;
}

extern "C" void kernel_launch(void* const* d_in, const int* in_sizes, int n_in,
                              void* d_out, int out_size, void* d_ws, size_t ws_size,
                              hipStream_t stream) {
    const int*   keys  = (const int*)d_in[0];
    const int*   mask  = (const int*)d_in[1];
    const float* table = (const float*)d_in[2];
    float*       out   = (float*)d_out;

    // 16 rows per 256-thread block; N = 106496 = 6656 * 16 (no tail).
    const int blocks = NROWS / 16;
    emb_pool_kernel<<<blocks, 256, 0, stream>>>(keys, mask, table, out);
}

// Round 7
// 333.232 us; speedup vs baseline: 1.0669x; 1.0278x over previous
//
#include <hip/hip_runtime.h>

// Embedding lookup sparse (combiner='sum') for MI355X.
// keys:  int32 [N=106496, NNZ=10]
// mask:  bool in reference -> delivered as int32 [N, NNZ] by the harness
// table: fp32  [VOCAB=1e6, DIM=64]  (~244 MiB)
// out:   fp32  [N, DIM]  == reshape(BATCH, SLOTS*DIM), same memory layout
//
// v3: branchless ILP + index redirection. Masked positions redirect their
// gather to table row 0 (cache-resident after first touch) instead of either
// (a) fetching a random unused row (v2: +30% HBM bytes) or (b) predicating
// with exec-mask regions (v1: serializes the 10 gathers, −38 us). All 10
// gathers stay in flight together; mask applied as exact 0/1 FMA.

constexpr int NNZ   = 10;
constexpr int NROWS = 4096 * 26;   // 106496
constexpr int DIM   = 64;

__global__ __launch_bounds__(256) void emb_pool_kernel(
    const int* __restrict__ keys,
    const int* __restrict__ mask,     // int32: 0 or 1 per (row, j)
    const float* __restrict__ table,
    float* __restrict__ out)
{
    const int tid      = threadIdx.x;
    const int g        = tid & 15;        // float4 slice within the row (16 B/lane)
    const int rowLocal = tid >> 4;        // 0..15
    const int row      = blockIdx.x * 16 + rowLocal;

    const int* krow = keys + (size_t)row * NNZ;
    const int* mrow = mask + (size_t)row * NNZ;

    // Key/mask rows are 40 B (8 B-aligned) -> int2 vector loads.
    int k[NNZ], m[NNZ];
#pragma unroll
    for (int j = 0; j < NNZ; j += 2) {
        *reinterpret_cast<int2*>(k + j) = *reinterpret_cast<const int2*>(krow + j);
        *reinterpret_cast<int2*>(m + j) = *reinterpret_cast<const int2*>(mrow + j);
    }

    // Redirect masked gathers to row 0 (one v_cndmask each, no divergence).
    // Row 0 is hit by ~30% of all gathers -> L1/L2 resident -> ~no HBM cost.
#pragma unroll
    for (int j = 0; j < NNZ; ++j) {
        k[j] = (m[j] != 0) ? k[j] : 0;
    }

    // All 10 gathers in flight at once.
    float4 v[NNZ];
#pragma unroll
    for (int j = 0; j < NNZ; ++j) {
        v[j] = *reinterpret_cast<const float4*>(
            table + (size_t)k[j] * DIM + g * 4);
    }

    float4 acc = make_float4(0.f, 0.f, 0.f, 0.f);
#pragma unroll
    for (int j = 0; j < NNZ; ++j) {
        const float mf = (float)m[j];   // 0.0f or 1.0f
        acc.x = fmaf(mf, v[j].x, acc.x);
        acc.y = fmaf(mf, v[j].y, acc.y);
        acc.z = fmaf(mf, v[j].z, acc.z);
        acc.w = fmaf(mf, v[j].w, acc.w);
    }
    *reinterpret_cast<float4*>(out + (size_t)row * DIM + g * 4) = acc;
}

extern "C" void kernel_launch(void* const* d_in, const int* in_sizes, int n_in,
                              void* d_out, int out_size, void* d_ws, size_t ws_size,
                              hipStream_t stream) {
    const int*   keys  = (const int*)d_in[0];
    const int*   mask  = (const int*)d_in[1];
    const float* table = (const float*)d_in[2];
    float*       out   = (float*)d_out;

    // 16 rows per 256-thread block; N = 106496 = 6656 * 16 (no tail).
    const int blocks = NROWS / 16;
    emb_pool_kernel<<<blocks, 256, 0, stream>>>(keys, mask, table, out);
}